// Round 14
// baseline (53.005 us; speedup 1.0000x reference)
//
#include <hip/hip_runtime.h>
#include <math.h>

#define BLOCK 256
#define QPT 8     // queries per thread
#define CS  64    // refs per chunk (local idx 0..63 in masked low key bits)

typedef unsigned long long u64;
typedef _Float16 f16;
typedef _Float16 f16x2 __attribute__((ext_vector_type(2)));

union HU { f16 h; unsigned short u; };
static __device__ __forceinline__ unsigned short h16(float x) { HU v; v.h = (f16)x; return v.u; }
union U2H { unsigned u; f16x2 h; };

// Setup: pack refs as (f16 -2x | f16 -2y, f32 -2z, f32 ||r||^2+64, 0) —
// every halfword a constructed finite f16 (R10 lesson: never reinterpret raw
// bits as f16 operands). Also init part sentinels and zero out: one dispatch,
// no memsets. packed: [B*N dir0 refs = dst][B*M dir1 refs = src].
__global__ void chamfer_setup_kernel(const float* __restrict__ pc_src,
                                     const float* __restrict__ pc_dst,
                                     uint4* __restrict__ packed,
                                     u64* __restrict__ part,
                                     float* __restrict__ out,
                                     int M, int N, int B) {
    const int t = blockIdx.x * BLOCK + threadIdx.x;
    const int TOT0 = B * N;
    const int dir = (t >= TOT0);
    const int NR = dir ? M : N;
    const float* pc = dir ? pc_src : pc_dst;
    const int tt = dir ? t - TOT0 : t;
    const int b = tt / NR, i = tt - b * NR;
    const float* rb = pc + (size_t)b * 3 * NR;
    const float rx = rb[i], ry = rb[NR + i], rz = rb[2 * NR + i];
    uint4 v;
    v.x = (unsigned)h16(-2.0f * rx) | ((unsigned)h16(-2.0f * ry) << 16);
    v.y = __float_as_uint(-2.0f * rz);
    v.z = __float_as_uint(fmaf(rx, rx, fmaf(ry, ry, rz * rz)) + 64.0f);
    v.w = 0u;
    packed[t] = v;
    part[t] = ~0ull;                 // same element count B*(M+N)
    if (t == 0) *out = 0.0f;
}

// Min-scan, no LDS (R13 structure, absmax 0.0 verified). Hot-loop core uses
// v_dot2_f32_f16 to fold the x,y terms: per pair
//   u = dot2(q_xy, r_xy) + w   (f16 inputs, f32 accumulate — same precision
//                               class as the R9/R12 MFMA path, verified 0.0)
//   e = fma(qz, rz, u)         (z and w stay full f32)
//   key = (bits(e) & ~63) | i ; kmin = min(kmin, key)
// = 5 VALU slots/pair vs R13's 6. e = d^2 + 64 - ||q||^2 > 0 so u32 order ==
// float order; low 6 bits carry the local ref idx (the reduce kernel
// recomputes the winning distance EXACTLY from raw f32 coords). Epilogue:
// one device-scope atomicMin(u64) per (query, chunk), key =
// (masked_e << 32) | global_idx — commutative/idempotent => deterministic;
// ties pick lowest global index (jnp.argmin first-occurrence).
__global__ __launch_bounds__(BLOCK, 8)
void chamfer_min_kernel(const uint4* __restrict__ packed,
                        const float* __restrict__ pc_src,
                        const float* __restrict__ pc_dst,
                        u64* __restrict__ part,
                        int M, int N, int B, int Zc0) {
    const int b = blockIdx.y;
    const int z = blockIdx.z;
    const int dir = (z >= Zc0) ? 1 : 0;
    const int chunk = dir ? (z - Zc0) : z;

    const int NQ = dir ? N : M;
    const float* pcq = dir ? pc_dst : pc_src;
    const uint4* rp = packed
        + (dir ? (size_t)B * N + (size_t)b * M : (size_t)b * N)
        + (size_t)chunk * CS;
    u64* pp = part + (dir ? (size_t)B * M : (size_t)0) + (size_t)b * NQ;

    const int tid = threadIdx.x;
    const int q0 = blockIdx.x * (BLOCK * QPT) + tid;
    const float* qb = pcq + (size_t)b * 3 * NQ;

    f16x2 qxy[QPT];
    float qz[QPT];
    unsigned kmin[QPT];
#pragma unroll
    for (int j = 0; j < QPT; ++j) {
        const int q = q0 + j * BLOCK;
        qxy[j] = (f16x2){(f16)qb[q], (f16)qb[NQ + q]};
        qz[j] = qb[2 * NQ + q];
        kmin[j] = 0xFFFFFFFFu;
    }

#pragma unroll 8
    for (int i = 0; i < CS; ++i) {
        const uint4 rv = rp[i];          // wave-uniform address
        U2H rxy; rxy.u = rv.x;
        const float rz = __uint_as_float(rv.y);
        const float wv = __uint_as_float(rv.z);
        const unsigned idx = (unsigned)i;
#pragma unroll
        for (int j = 0; j < QPT; ++j) {
#if __has_builtin(__builtin_amdgcn_fdot2)
            const float u = __builtin_amdgcn_fdot2(qxy[j], rxy.h, wv, false);
#else
            const float u = fmaf((float)qxy[j].x, (float)rxy.h.x,
                            fmaf((float)qxy[j].y, (float)rxy.h.y, wv));
#endif
            const float e = fmaf(qz[j], rz, u);
            const unsigned key = (__float_as_uint(e) & ~63u) | idx;
            kmin[j] = key < kmin[j] ? key : kmin[j];
        }
    }

    const unsigned n0 = (unsigned)(chunk * CS);
#pragma unroll
    for (int j = 0; j < QPT; ++j) {
        const int q = q0 + j * BLOCK;
        const u64 key = ((u64)(kmin[j] & ~63u) << 32) | (u64)(n0 + (kmin[j] & 63u));
        atomicMin(&pp[q], key);
    }
}

// Epilogue: one thread per query (both directions concatenated in part).
// Low 32 bits of key64 = global argmin ref index; recompute the winning
// distance EXACTLY from raw f32 coords, weight by sigma, block-reduce,
// one atomicAdd per block.
__global__ void chamfer_reduce_kernel(const float* __restrict__ pc_src,
                                      const float* __restrict__ pc_dst,
                                      const float* __restrict__ sig_src,
                                      const float* __restrict__ sig_dst,
                                      const u64* __restrict__ part,
                                      float* __restrict__ out,
                                      int M, int N, int B) {
    __shared__ float red[BLOCK];
    const int TT = blockIdx.x * BLOCK + threadIdx.x;
    const int dir = (TT >= B * M);           // uniform per block (B*M % 256 == 0)
    const int t = dir ? TT - B * M : TT;     // t = b*NQ + q

    const int NQ = dir ? N : M;
    const int NR = dir ? M : N;
    const float* pcq  = dir ? pc_dst : pc_src;
    const float* pcr  = dir ? pc_src : pc_dst;
    const float* sigq = dir ? sig_dst : sig_src;
    const float* sigr = dir ? sig_src : sig_dst;
    const float scale = 1.0f / (float)(B * NQ);

    const int b = t / NQ;
    const int q = t - b * NQ;

    const int gidx = (int)(unsigned)part[TT];

    const float* qbase = pcq + (size_t)b * 3 * NQ;
    const float* rbase = pcr + (size_t)b * 3 * NR;
    const float dx = qbase[q]          - rbase[gidx];
    const float dy = qbase[NQ + q]     - rbase[NR + gidx];
    const float dz = qbase[2 * NQ + q] - rbase[2 * NR + gidx];
    const float dist = sqrtf(fmaf(dx, dx, fmaf(dy, dy, dz * dz)));

    const float s = 0.5f * (sigq[t] + sigr[(size_t)b * NR + gidx]);
    red[threadIdx.x] = dist * s * scale;
    __syncthreads();

    for (int w = BLOCK / 2; w > 0; w >>= 1) {
        if (threadIdx.x < w) red[threadIdx.x] += red[threadIdx.x + w];
        __syncthreads();
    }
    if (threadIdx.x == 0) atomicAdd(out, red[0]);
}

extern "C" void kernel_launch(void* const* d_in, const int* in_sizes, int n_in,
                              void* d_out, int out_size, void* d_ws, size_t ws_size,
                              hipStream_t stream) {
    const float* pc_src  = (const float*)d_in[0];   // [B,3,M]
    const float* pc_dst  = (const float*)d_in[1];   // [B,3,N]
    const float* sig_src = (const float*)d_in[2];   // [B,M]
    const float* sig_dst = (const float*)d_in[3];   // [B,N]
    float* out = (float*)d_out;

    const int B = 8;
    const int M = in_sizes[2] / B;   // 4096
    const int N = in_sizes[3] / B;   // 4096

    // d_ws layout: part (B*(M+N) u64 = 512 KiB) | packed (B*(M+N) uint4 = 1 MiB)
    u64* part = (u64*)d_ws;
    uint4* packed = (uint4*)((char*)d_ws + (size_t)B * (M + N) * sizeof(u64));

    const int TOT = B * (M + N);     // 65536

    {   // setup: pack refs + sentinels + zero out (no memsets)
        chamfer_setup_kernel<<<TOT / BLOCK, BLOCK, 0, stream>>>(
            pc_src, pc_dst, packed, part, out, M, N, B);
    }
    {   // min-scan, both directions: grid (2, 8, 128) = 2048 blocks, no LDS
        const int Zc0 = N / CS;
        const int Zc1 = M / CS;
        dim3 grid(M / (BLOCK * QPT), B, Zc0 + Zc1);
        chamfer_min_kernel<<<grid, BLOCK, 0, stream>>>(
            packed, pc_src, pc_dst, part, M, N, B, Zc0);
    }
    {   // epilogue over all queries of both directions
        dim3 rgrid(TOT / BLOCK);
        chamfer_reduce_kernel<<<rgrid, BLOCK, 0, stream>>>(
            pc_src, pc_dst, sig_src, sig_dst, part, out, M, N, B);
    }
}

// Round 15
// 50.845 us; speedup vs baseline: 1.0425x; 1.0425x over previous
//
#include <hip/hip_runtime.h>
#include <math.h>

#define BLOCK 256
#define QPT 8     // queries per thread (named registers, never arrays)
#define CS  64    // refs per chunk (local idx 0..63 in masked low key bits)

typedef unsigned long long u64;

// Setup: pack refs into uniform-loadable uint4(-2x,-2y,-2z, ||r||^2+64),
// init part sentinels, zero out. One dispatch, no memsets.
// packed: [B*N dir0 refs = dst][B*M dir1 refs = src]; part: [B*M][B*N].
__global__ void chamfer_setup_kernel(const float* __restrict__ pc_src,
                                     const float* __restrict__ pc_dst,
                                     uint4* __restrict__ packed,
                                     u64* __restrict__ part,
                                     float* __restrict__ out,
                                     int M, int N, int B) {
    const int t = blockIdx.x * BLOCK + threadIdx.x;
    const int TOT0 = B * N;
    const int dir = (t >= TOT0);
    const int NR = dir ? M : N;
    const float* pc = dir ? pc_src : pc_dst;
    const int tt = dir ? t - TOT0 : t;
    const int b = tt / NR, i = tt - b * NR;
    const float* rb = pc + (size_t)b * 3 * NR;
    const float rx = rb[i], ry = rb[NR + i], rz = rb[2 * NR + i];
    uint4 v;
    v.x = __float_as_uint(-2.0f * rx);
    v.y = __float_as_uint(-2.0f * ry);
    v.z = __float_as_uint(-2.0f * rz);
    v.w = __float_as_uint(fmaf(rx, rx, fmaf(ry, ry, rz * rz)) + 64.0f);
    packed[t] = v;
    part[t] = ~0ull;                 // same element count B*(M+N)
    if (t == 0) *out = 0.0f;
}

// R13 structure (absmax 0.0 verified), with the register-starvation fix:
// R13's VGPR_Count=28 < the >=36 live values its unrolled state needs — the
// allocator was spilling/reloading query coords INSIDE the 64-iter hot loop
// (the ~2-3 phantom slots/pair + ~30% idle seen in every plateau variant).
// Fix: __launch_bounds__(256,4) (128-VGPR budget) + all per-thread state in
// NAMED scalars (no arrays -> nothing can be lowered to scratch).
// Hot loop/pair: 3 v_fma + v_and_or + v_min = 5 slots, refs via wave-uniform
// s_load_dwordx4. e = d^2 + 64 - ||q||^2 > 0 so u32 order == float order;
// low 6 bits carry local ref idx (reduce recomputes the winning distance
// EXACTLY from raw f32). Epilogue: device-scope atomicMin(u64) per
// (query, chunk), key = (masked_e << 32) | global_idx — commutative and
// idempotent => deterministic; ties pick lowest global index (jnp.argmin
// first-occurrence).
#define LOADQ(n)                                                        \
    float q##n##x, q##n##y, q##n##z; unsigned k##n;                     \
    { const int q = q0 + n * BLOCK;                                     \
      q##n##x = qb[q]; q##n##y = qb[NQ + q]; q##n##z = qb[2 * NQ + q];  \
      k##n = 0xFFFFFFFFu; }

#define QSTEP(n)                                                        \
    { const float e = fmaf(q##n##x, rx,                                 \
                      fmaf(q##n##y, ry, fmaf(q##n##z, rz, wv)));        \
      const unsigned key = (__float_as_uint(e) & ~63u) | idx;           \
      k##n = key < k##n ? key : k##n; }

#define EMITK(n)                                                        \
    { const int q = q0 + n * BLOCK;                                     \
      const u64 key = ((u64)(k##n & ~63u) << 32) | (u64)(n0 + (k##n & 63u)); \
      atomicMin(&pp[q], key); }

__global__ __launch_bounds__(BLOCK, 4)
void chamfer_min_kernel(const uint4* __restrict__ packed,
                        const float* __restrict__ pc_src,
                        const float* __restrict__ pc_dst,
                        u64* __restrict__ part,
                        int M, int N, int B, int Zc0) {
    const int b = blockIdx.y;
    const int z = blockIdx.z;
    const int dir = (z >= Zc0) ? 1 : 0;
    const int chunk = dir ? (z - Zc0) : z;

    const int NQ = dir ? N : M;
    const float* pcq = dir ? pc_dst : pc_src;
    const uint4* rp = packed
        + (dir ? (size_t)B * N + (size_t)b * M : (size_t)b * N)
        + (size_t)chunk * CS;
    u64* pp = part + (dir ? (size_t)B * M : (size_t)0) + (size_t)b * NQ;

    const int tid = threadIdx.x;
    const int q0 = blockIdx.x * (BLOCK * QPT) + tid;
    const float* qb = pcq + (size_t)b * 3 * NQ;

    LOADQ(0) LOADQ(1) LOADQ(2) LOADQ(3)
    LOADQ(4) LOADQ(5) LOADQ(6) LOADQ(7)

#pragma unroll 4
    for (int i = 0; i < CS; ++i) {
        const uint4 rv = rp[i];          // wave-uniform -> s_load_dwordx4
        const float rx = __uint_as_float(rv.x);
        const float ry = __uint_as_float(rv.y);
        const float rz = __uint_as_float(rv.z);
        const float wv = __uint_as_float(rv.w);
        const unsigned idx = (unsigned)i;
        QSTEP(0) QSTEP(1) QSTEP(2) QSTEP(3)
        QSTEP(4) QSTEP(5) QSTEP(6) QSTEP(7)
    }

    const unsigned n0 = (unsigned)(chunk * CS);
    EMITK(0) EMITK(1) EMITK(2) EMITK(3)
    EMITK(4) EMITK(5) EMITK(6) EMITK(7)
}

// Epilogue: one thread per query (both directions concatenated in part).
// Low 32 bits of key64 = global argmin ref index; recompute the winning
// distance EXACTLY from raw f32 coords, weight by sigma, block-reduce,
// one atomicAdd per block.
__global__ void chamfer_reduce_kernel(const float* __restrict__ pc_src,
                                      const float* __restrict__ pc_dst,
                                      const float* __restrict__ sig_src,
                                      const float* __restrict__ sig_dst,
                                      const u64* __restrict__ part,
                                      float* __restrict__ out,
                                      int M, int N, int B) {
    __shared__ float red[BLOCK];
    const int TT = blockIdx.x * BLOCK + threadIdx.x;
    const int dir = (TT >= B * M);           // uniform per block (B*M % 256 == 0)
    const int t = dir ? TT - B * M : TT;     // t = b*NQ + q

    const int NQ = dir ? N : M;
    const int NR = dir ? M : N;
    const float* pcq  = dir ? pc_dst : pc_src;
    const float* pcr  = dir ? pc_src : pc_dst;
    const float* sigq = dir ? sig_dst : sig_src;
    const float* sigr = dir ? sig_src : sig_dst;
    const float scale = 1.0f / (float)(B * NQ);

    const int b = t / NQ;
    const int q = t - b * NQ;

    const int gidx = (int)(unsigned)part[TT];

    const float* qbase = pcq + (size_t)b * 3 * NQ;
    const float* rbase = pcr + (size_t)b * 3 * NR;
    const float dx = qbase[q]          - rbase[gidx];
    const float dy = qbase[NQ + q]     - rbase[NR + gidx];
    const float dz = qbase[2 * NQ + q] - rbase[2 * NR + gidx];
    const float dist = sqrtf(fmaf(dx, dx, fmaf(dy, dy, dz * dz)));

    const float s = 0.5f * (sigq[t] + sigr[(size_t)b * NR + gidx]);
    red[threadIdx.x] = dist * s * scale;
    __syncthreads();

    for (int w = BLOCK / 2; w > 0; w >>= 1) {
        if (threadIdx.x < w) red[threadIdx.x] += red[threadIdx.x + w];
        __syncthreads();
    }
    if (threadIdx.x == 0) atomicAdd(out, red[0]);
}

extern "C" void kernel_launch(void* const* d_in, const int* in_sizes, int n_in,
                              void* d_out, int out_size, void* d_ws, size_t ws_size,
                              hipStream_t stream) {
    const float* pc_src  = (const float*)d_in[0];   // [B,3,M]
    const float* pc_dst  = (const float*)d_in[1];   // [B,3,N]
    const float* sig_src = (const float*)d_in[2];   // [B,M]
    const float* sig_dst = (const float*)d_in[3];   // [B,N]
    float* out = (float*)d_out;

    const int B = 8;
    const int M = in_sizes[2] / B;   // 4096
    const int N = in_sizes[3] / B;   // 4096

    // d_ws layout: part (B*(M+N) u64 = 512 KiB) | packed (B*(M+N) uint4 = 1 MiB)
    u64* part = (u64*)d_ws;
    uint4* packed = (uint4*)((char*)d_ws + (size_t)B * (M + N) * sizeof(u64));

    const int TOT = B * (M + N);     // 65536

    {   // setup: pack refs + sentinels + zero out (no memsets)
        chamfer_setup_kernel<<<TOT / BLOCK, BLOCK, 0, stream>>>(
            pc_src, pc_dst, packed, part, out, M, N, B);
    }
    {   // min-scan, both directions: grid (2, 8, 128) = 2048 blocks, no LDS
        const int Zc0 = N / CS;
        const int Zc1 = M / CS;
        dim3 grid(M / (BLOCK * QPT), B, Zc0 + Zc1);
        chamfer_min_kernel<<<grid, BLOCK, 0, stream>>>(
            packed, pc_src, pc_dst, part, M, N, B, Zc0);
    }
    {   // epilogue over all queries of both directions
        dim3 rgrid(TOT / BLOCK);
        chamfer_reduce_kernel<<<rgrid, BLOCK, 0, stream>>>(
            pc_src, pc_dst, sig_src, sig_dst, part, out, M, N, B);
    }
}